// Round 8
// baseline (2241.494 us; speedup 1.0000x reference)
//
#include <hip/hip_runtime.h>
#include <hip/hip_bf16.h>
#include <cstdint>

#define Bb 64
#define Cc 64
#define Tt 2048
#define Hh 128
#define RING 18
#define HRS 1024   // dw per h ring slot: 4 kk-groups * 64 granules * 4 dw
#define XPS 524    // dw per x ss-plane: 2 kk-groups * 64 granules * 4 dw = 512, +12 pad (524%8=4 -> tq spread)

typedef __fp16 h2    __attribute__((ext_vector_type(2)));
typedef __fp16 f16x8 __attribute__((ext_vector_type(8)));
typedef float  f32x4 __attribute__((ext_vector_type(4)));

union P8 { uint4 u; f16x8 v; h2 p[4]; __fp16 h[8]; };
union P2 { unsigned int u; h2 p; };

#if __has_builtin(__builtin_amdgcn_exp2f)
#define EXP2F(v) __builtin_amdgcn_exp2f(v)
#else
#define EXP2F(v) __expf(0.69314718056f * (v))
#endif
#define RCPF(v) __builtin_amdgcn_rcpf(v)
#define L2E 1.44269504089f

__device__ __forceinline__ float ftanh(float xx) {
    return 1.0f - 2.0f / (__expf(2.0f * xx) + 1.0f);
}

__device__ __forceinline__ f16x8 cvt8s(float4 a, float4 b, float s) {
    P8 u;
    u.p[0] = __builtin_amdgcn_cvt_pkrtz(a.x * s, a.y * s);
    u.p[1] = __builtin_amdgcn_cvt_pkrtz(a.z * s, a.w * s);
    u.p[2] = __builtin_amdgcn_cvt_pkrtz(b.x * s, b.y * s);
    u.p[3] = __builtin_amdgcn_cvt_pkrtz(b.z * s, b.w * s);
    return u.v;
}

// ---------------- Kernel 1: MFMA bidirectional LSTM ----------------
// grid 8 = dir*4 + bgroup, block 512 (8 waves), 16 sequences per block.
// Z^T = Whh@h^T + Wih@x^T via mfma_f32_16x16x32_f16; M=512 gates, N=16 batch,
// K=128+64. LDS panels stored FRAG-MAJOR: per kk-group, 64 granules of 16B,
// granule g' = hi*16 + (b^hi) (XOR swizzle) -> MFMA B-reads are lane-linear
// contiguous (conflict-free); act h-write is one b64/lane (floor); x staging
// uses paired-channel dword writes (<=2-way). One barrier/step; y flushed
// from the h-ring once per 16-step tile.
__global__ __launch_bounds__(512, 2) void lstm_kernel(
    const float* __restrict__ x,
    const float* __restrict__ Wih_f, const float* __restrict__ Whh_f,
    const float* __restrict__ bih_f, const float* __restrict__ bhh_f,
    const float* __restrict__ Wih_b, const float* __restrict__ Whh_b,
    const float* __restrict__ bih_b, const float* __restrict__ bhh_b,
    __fp16* __restrict__ y)
{
    const int blk = blockIdx.x;
    const int dir = blk >> 2;
    const int bg  = blk & 3;
    const int tid = threadIdx.x;
    const int w   = tid >> 6;      // wave 0..7 -> j in [16w,16w+16)
    const int l   = tid & 63;
    const int col = l & 15;        // N-dim: batch slot
    const int hi  = l >> 4;        // k-group / row-group

    const float* Wih = dir ? Wih_b : Wih_f;
    const float* Whh = dir ? Whh_b : Whh_f;
    const float* bih = dir ? bih_b : bih_f;
    const float* bhh = dir ? bhh_b : bhh_f;

    f16x8 whA[4][4];
    f16x8 wxA[4][2];
    float bias[4][4];
    float cst[4] = {0.0f, 0.0f, 0.0f, 0.0f};
    #pragma unroll
    for (int m = 0; m < 4; ++m) {
        const float s = (m == 2) ? (2.0f * L2E) : L2E;
        const int rowA = (m << 7) + (w << 4) + col;
        #pragma unroll
        for (int kk = 0; kk < 4; ++kk) {
            const float* p = Whh + (size_t)rowA * 128 + kk * 32 + hi * 8;
            whA[m][kk] = cvt8s(*(const float4*)p, *(const float4*)(p + 4), s);
        }
        #pragma unroll
        for (int kk = 0; kk < 2; ++kk) {
            const float* p = Wih + (size_t)rowA * 64 + kk * 32 + hi * 8;
            wxA[m][kk] = cvt8s(*(const float4*)p, *(const float4*)(p + 4), s);
        }
        #pragma unroll
        for (int r = 0; r < 4; ++r) {
            const int rowC = (m << 7) + (w << 4) + (hi << 2) + r;
            bias[m][r] = (bih[rowC] + bhh[rowC]) * s;
        }
    }

    __shared__ __align__(16) unsigned int lds_hr[RING * HRS];
    __shared__ __align__(16) unsigned int lds_xs[16 * XPS];

    // zero initial-h ring slot
    for (int i = tid; i < HRS; i += 512) lds_hr[(RING - 1) * HRS + i] = 0u;

    // per-thread constant addresses
    const int gsw = ((hi << 4) + (col ^ hi)) << 2;             // B-frag read granule (dw)
    const int hiw = ((w & 1) << 1) + (hi >> 1);
    const int wgsw = ((w >> 1) << 8) + (((hiw << 4) + (col ^ hiw)) << 2) + ((hi & 1) << 1); // h-write (dw)

    const size_t xbase = (size_t)(bg * 16) * Cc * Tt;
    int slp = RING - 1;
    int slc = 0;

    #pragma unroll 1
    for (int tile = 0; tile < Tt / 16; ++tile) {
        const int s0  = tile << 4;
        const int sl0 = slc;

        // ---- stage x tile (frag-major, paired channels -> dword writes) ----
        #pragma unroll
        for (int it = 0; it < 4; ++it) {
            int i = tid + (it << 9);
            int tq = i & 3, cp = (i >> 2) & 31, b = i >> 7;
            int tb = dir ? (Tt - 4 - s0 - (tq << 2)) : (s0 + (tq << 2));
            const float* rA = x + xbase + ((size_t)b * Cc + 2 * cp) * Tt + tb;
            float4 va = *(const float4*)rA;
            float4 vb = *(const float4*)(rA + Tt);
            const float* pa = (const float*)&va;
            const float* pb = (const float*)&vb;
            int kk = cp >> 4, hip = (cp >> 2) & 3, e2 = cp & 3;
            int gdst = (kk << 8) + (((hip << 4) + (b ^ hip)) << 2) + e2;
            #pragma unroll
            for (int e = 0; e < 4; ++e) {
                int ss = dir ? ((tq << 2) + 3 - e) : ((tq << 2) + e);
                P2 pk; pk.p = __builtin_amdgcn_cvt_pkrtz(pa[e], pb[e]);
                lds_xs[ss * XPS + gdst] = pk.u;
            }
        }
        __syncthreads();   // drains stage writes + previous flush stores

        // ---- 16 recurrent steps, no vmem ----
        #pragma unroll 1
        for (int ss = 0; ss < 16; ++ss) {
            const unsigned int* hbase = lds_hr + slp * HRS;
            const unsigned int* xbase2 = lds_xs + ss * XPS;
            P8 hB[4], xB[2];
            #pragma unroll
            for (int kk = 0; kk < 4; ++kk)
                hB[kk].u = *(const uint4*)(hbase + (kk << 8) + gsw);
            #pragma unroll
            for (int kk = 0; kk < 2; ++kk)
                xB[kk].u = *(const uint4*)(xbase2 + (kk << 8) + gsw);

            f32x4 acc[4];
            #pragma unroll
            for (int m = 0; m < 4; ++m) {
                f32x4 a = {0.0f, 0.0f, 0.0f, 0.0f};
                #pragma unroll
                for (int kk = 0; kk < 4; ++kk)
                    a = __builtin_amdgcn_mfma_f32_16x16x32_f16(whA[m][kk], hB[kk].v, a, 0, 0, 0);
                #pragma unroll
                for (int kk = 0; kk < 2; ++kk)
                    a = __builtin_amdgcn_mfma_f32_16x16x32_f16(wxA[m][kk], xB[kk].v, a, 0, 0, 0);
                acc[m] = a;
            }

            float hhv[4];
            #pragma unroll
            for (int r = 0; r < 4; ++r) {
                float zi = acc[0][r] + bias[0][r];
                float zf = acc[1][r] + bias[1][r];
                float zg = acc[2][r] + bias[2][r];
                float zo = acc[3][r] + bias[3][r];
                float si = RCPF(1.0f + EXP2F(-zi));
                float sf = RCPF(1.0f + EXP2F(-zf));
                float so = RCPF(1.0f + EXP2F(-zo));
                float tg = fmaf(-2.0f, RCPF(1.0f + EXP2F(zg)), 1.0f);
                float c  = fmaf(sf, cst[r], si * tg);
                cst[r] = c;
                float tc = fmaf(-2.0f, RCPF(1.0f + EXP2F(2.0f * L2E * c)), 1.0f);
                hhv[r] = so * tc;
            }
            P2 hp0, hp1;
            hp0.p = __builtin_amdgcn_cvt_pkrtz(hhv[0], hhv[1]);
            hp1.p = __builtin_amdgcn_cvt_pkrtz(hhv[2], hhv[3]);
            uint2 wv; wv.x = hp0.u; wv.y = hp1.u;
            *(uint2*)(lds_hr + slc * HRS + wgsw) = wv;
            __syncthreads();
            slp = slc;
            slc = (slc + 1 == RING) ? 0 : slc + 1;
        }

        // ---- flush y for this tile (granule-linear LDS reads, conflict-free) ----
        #pragma unroll
        for (int it = 0; it < 8; ++it) {
            int idx = (it << 3) + w;          // 0..63 -> (ss, kkf)
            int ssf = idx >> 2, kkf = idx & 3;
            int sl = sl0 + ssf; if (sl >= RING) sl -= RING;
            uint4 v = *(const uint4*)(lds_hr + sl * HRS + (kkf << 8) + (l << 2));
            int bf = (l & 15) ^ (l >> 4);
            int j8 = (kkf << 2) + (l >> 4);
            int t = dir ? (Tt - 1 - (s0 + ssf)) : (s0 + ssf);
            *(uint4*)(y + (((size_t)(bg * 16 + bf) * Tt + t) << 8) + dir * 128 + (j8 << 3)) = v;
        }
    }
}

// ---------------- Kernel 2: attention scores (MFMA) ----------------
__global__ __launch_bounds__(512, 2) void attn_scores_kernel(
    const __fp16* __restrict__ y,
    const float* __restrict__ Wa, const float* __restrict__ ba,
    const float* __restrict__ Wu, const float* __restrict__ bu,
    float* __restrict__ scores)
{
    const int b   = blockIdx.y;
    const int t0  = blockIdx.x * 64;
    const int tid = threadIdx.x;
    const int w   = tid >> 6, l = tid & 63;
    const int col = l & 15, hi = l >> 4;

    __shared__ __fp16 y_lds[64][264];
    __shared__ float red[8][64];

    f16x8 wB[2][8];
    float bav[2], wuv[2];
    #pragma unroll
    for (int ns = 0; ns < 2; ++ns) {
        const int g = (w << 5) + (ns << 4) + col;
        #pragma unroll
        for (int kk = 0; kk < 8; ++kk) {
            const float* p = Wa + (size_t)g * 256 + kk * 32 + hi * 8;
            wB[ns][kk] = cvt8s(*(const float4*)p, *(const float4*)(p + 4), 1.0f);
        }
        bav[ns] = ba[g];
        wuv[ns] = Wu[g];
    }

    #pragma unroll
    for (int it = 0; it < 4; ++it) {
        int i = tid + it * 512;
        int tt = i >> 5, c8 = i & 31;
        uint4 v = *(const uint4*)(y + ((size_t)b * Tt + t0 + tt) * 256 + c8 * 8);
        *(uint4*)&y_lds[tt][c8 * 8] = v;
    }
    __syncthreads();

    f32x4 acc[4][2];
    #pragma unroll
    for (int ms = 0; ms < 4; ++ms)
        #pragma unroll
        for (int ns = 0; ns < 2; ++ns) {
            acc[ms][ns][0] = bav[ns]; acc[ms][ns][1] = bav[ns];
            acc[ms][ns][2] = bav[ns]; acc[ms][ns][3] = bav[ns];
        }

    #pragma unroll
    for (int ms = 0; ms < 4; ++ms) {
        #pragma unroll
        for (int kk = 0; kk < 8; ++kk) {
            P8 a;
            a.u = *(const uint4*)&y_lds[(ms << 4) + col][kk * 32 + hi * 8];
            acc[ms][0] = __builtin_amdgcn_mfma_f32_16x16x32_f16(a.v, wB[0][kk], acc[ms][0], 0, 0, 0);
            acc[ms][1] = __builtin_amdgcn_mfma_f32_16x16x32_f16(a.v, wB[1][kk], acc[ms][1], 0, 0, 0);
        }
    }

    #pragma unroll
    for (int ms = 0; ms < 4; ++ms) {
        float pr[4];
        #pragma unroll
        for (int r = 0; r < 4; ++r) {
            pr[r] = wuv[0] * ftanh(acc[ms][0][r]) + wuv[1] * ftanh(acc[ms][1][r]);
            pr[r] += __shfl_xor(pr[r], 1, 64);
            pr[r] += __shfl_xor(pr[r], 2, 64);
            pr[r] += __shfl_xor(pr[r], 4, 64);
            pr[r] += __shfl_xor(pr[r], 8, 64);
        }
        if (col == 0) {
            #pragma unroll
            for (int r = 0; r < 4; ++r)
                red[w][(ms << 4) + (hi << 2) + r] = pr[r];
        }
    }
    __syncthreads();
    if (tid < 64) {
        float ssum = bu[0];
        #pragma unroll
        for (int wv = 0; wv < 8; ++wv) ssum += red[wv][tid];
        scores[(size_t)b * Tt + t0 + tid] = ssum;
    }
}

// ---------------- Kernel 3: softmax + weighted sum ----------------
__global__ __launch_bounds__(256) void attn_out_kernel(
    const __fp16* __restrict__ y,
    const float* __restrict__ scores,
    float* __restrict__ out)
{
    const int b = blockIdx.x;
    const int tid = threadIdx.x;
    const int lane = tid & 63, wid = tid >> 6;
    __shared__ float wls[2048];
    __shared__ float red[4];

    float m = -1e30f;
    for (int t = tid; t < Tt; t += 256) m = fmaxf(m, scores[(size_t)b * Tt + t]);
    #pragma unroll
    for (int off = 32; off >= 1; off >>= 1) m = fmaxf(m, __shfl_xor(m, off, 64));
    if (lane == 0) red[wid] = m;
    __syncthreads();
    m = fmaxf(fmaxf(red[0], red[1]), fmaxf(red[2], red[3]));
    __syncthreads();

    float sum = 0.0f;
    for (int t = tid; t < Tt; t += 256) {
        float e = __expf(scores[(size_t)b * Tt + t] - m);
        wls[t] = e;
        sum += e;
    }
    #pragma unroll
    for (int off = 32; off >= 1; off >>= 1) sum += __shfl_xor(sum, off, 64);
    if (lane == 0) red[wid] = sum;
    __syncthreads();
    const float inv = 1.0f / (red[0] + red[1] + red[2] + red[3]);

    const __fp16* yb = y + (size_t)b * Tt * 256 + tid;
    float acc = 0.0f;
    for (int t = 0; t < Tt; ++t) {
        acc += wls[t] * (float)yb[(size_t)t * 256];
    }
    out[b * 256 + tid] = acc * inv;
}

extern "C" void kernel_launch(void* const* d_in, const int* in_sizes, int n_in,
                              void* d_out, int out_size, void* d_ws, size_t ws_size,
                              hipStream_t stream) {
    const float* x     = (const float*)d_in[0];
    const float* Wih_f = (const float*)d_in[1];
    const float* Whh_f = (const float*)d_in[2];
    const float* bih_f = (const float*)d_in[3];
    const float* bhh_f = (const float*)d_in[4];
    const float* Wih_b = (const float*)d_in[5];
    const float* Whh_b = (const float*)d_in[6];
    const float* bih_b = (const float*)d_in[7];
    const float* bhh_b = (const float*)d_in[8];
    const float* Wa    = (const float*)d_in[9];
    const float* ba    = (const float*)d_in[10];
    const float* Wu    = (const float*)d_in[11];
    const float* bu    = (const float*)d_in[12];
    float* out = (float*)d_out;

    // workspace: y (B*T*256 f16 = 64 MiB) | scores (B*T f32 = 0.5 MiB)
    __fp16* y = (__fp16*)d_ws;
    float* scores = (float*)((char*)d_ws + (size_t)Bb * Tt * 256 * sizeof(__fp16));

    hipLaunchKernelGGL(lstm_kernel, dim3(8), dim3(512), 0, stream,
                       x, Wih_f, Whh_f, bih_f, bhh_f, Wih_b, Whh_b, bih_b, bhh_b, y);
    hipLaunchKernelGGL(attn_scores_kernel, dim3(Tt / 64, Bb), dim3(512), 0, stream,
                       y, Wa, ba, Wu, bu, scores);
    hipLaunchKernelGGL(attn_out_kernel, dim3(Bb), dim3(256), 0, stream, y, scores, out);
}

// Round 9
// 2132.632 us; speedup vs baseline: 1.0510x; 1.0510x over previous
//
#include <hip/hip_runtime.h>
#include <hip/hip_bf16.h>
#include <cstdint>

#define Bb 64
#define Cc 64
#define Tt 2048
#define Hh 128
#define RING 18
#define HRS 1024   // dw per h ring slot: 4 kk-groups * 64 granules * 4 dw
#define XPS 524    // dw per x ss-plane: 2 kk-groups * 64 granules * 4 dw = 512, +12 pad

typedef __fp16 h2    __attribute__((ext_vector_type(2)));
typedef __fp16 f16x8 __attribute__((ext_vector_type(8)));
typedef float  f32x4 __attribute__((ext_vector_type(4)));

union P8 { uint4 u; f16x8 v; h2 p[4]; __fp16 h[8]; };
union P2 { unsigned int u; h2 p; };

#if __has_builtin(__builtin_amdgcn_exp2f)
#define EXP2F(v) __builtin_amdgcn_exp2f(v)
#else
#define EXP2F(v) __expf(0.69314718056f * (v))
#endif
#define RCPF(v) __builtin_amdgcn_rcpf(v)
#define L2E 1.44269504089f

__device__ __forceinline__ float ftanh(float xx) {
    return 1.0f - 2.0f / (__expf(2.0f * xx) + 1.0f);
}

__device__ __forceinline__ f16x8 cvt8s(float4 a, float4 b, float s) {
    P8 u;
    u.p[0] = __builtin_amdgcn_cvt_pkrtz(a.x * s, a.y * s);
    u.p[1] = __builtin_amdgcn_cvt_pkrtz(a.z * s, a.w * s);
    u.p[2] = __builtin_amdgcn_cvt_pkrtz(b.x * s, b.y * s);
    u.p[3] = __builtin_amdgcn_cvt_pkrtz(b.z * s, b.w * s);
    return u.v;
}

// ---------------- Kernel 1: MFMA bidirectional LSTM ----------------
// grid 8 = dir*4 + bgroup, block 512 (8 waves), 16 sequences per block.
// Layouts identical to round 8 (frag-major granules, conflict-free).
// New schedule: per step s -> [4 h-MFMA chains (K=128)] || [x-MFMA for s+1
// into ping-pong xacc (bias as MFMA C-init)] || [8-trans fused activation].
// The x-part of step s+1 is h-independent, so its MFMAs + ds_reads overlap
// the activation's transcendental chain instead of phase-serializing.

// x-projection for step SS into DST (bias C-init):
#define XMFMA(DST, SS) do {                                                            \
    const unsigned int* xr_ = lds_xs + (SS) * XPS;                                     \
    P8 xb0_, xb1_;                                                                     \
    xb0_.u = *(const uint4*)(xr_ + gsw);                                               \
    xb1_.u = *(const uint4*)(xr_ + 256 + gsw);                                         \
    DST[0] = __builtin_amdgcn_mfma_f32_16x16x32_f16(wxA[0][0], xb0_.v, biasv[0], 0, 0, 0); \
    DST[1] = __builtin_amdgcn_mfma_f32_16x16x32_f16(wxA[1][0], xb0_.v, biasv[1], 0, 0, 0); \
    DST[2] = __builtin_amdgcn_mfma_f32_16x16x32_f16(wxA[2][0], xb0_.v, biasv[2], 0, 0, 0); \
    DST[3] = __builtin_amdgcn_mfma_f32_16x16x32_f16(wxA[3][0], xb0_.v, biasv[3], 0, 0, 0); \
    DST[0] = __builtin_amdgcn_mfma_f32_16x16x32_f16(wxA[0][1], xb1_.v, DST[0], 0, 0, 0);   \
    DST[1] = __builtin_amdgcn_mfma_f32_16x16x32_f16(wxA[1][1], xb1_.v, DST[1], 0, 0, 0);   \
    DST[2] = __builtin_amdgcn_mfma_f32_16x16x32_f16(wxA[2][1], xb1_.v, DST[2], 0, 0, 0);   \
    DST[3] = __builtin_amdgcn_mfma_f32_16x16x32_f16(wxA[3][1], xb1_.v, DST[3], 0, 0, 0);   \
} while (0)

#define LSTM_STEP(SS, CUR, NXT, DO_NX) do {                                            \
    const unsigned int* hbase_ = lds_hr + slp * HRS;                                   \
    P8 hB0_, hB1_, hB2_, hB3_;                                                         \
    hB0_.u = *(const uint4*)(hbase_ + 0 * 256 + gsw);                                  \
    hB1_.u = *(const uint4*)(hbase_ + 1 * 256 + gsw);                                  \
    hB2_.u = *(const uint4*)(hbase_ + 2 * 256 + gsw);                                  \
    hB3_.u = *(const uint4*)(hbase_ + 3 * 256 + gsw);                                  \
    f32x4 a0_ = __builtin_amdgcn_mfma_f32_16x16x32_f16(whA[0][0], hB0_.v, CUR[0], 0, 0, 0); \
    f32x4 a1_ = __builtin_amdgcn_mfma_f32_16x16x32_f16(whA[1][0], hB0_.v, CUR[1], 0, 0, 0); \
    f32x4 a2_ = __builtin_amdgcn_mfma_f32_16x16x32_f16(whA[2][0], hB0_.v, CUR[2], 0, 0, 0); \
    f32x4 a3_ = __builtin_amdgcn_mfma_f32_16x16x32_f16(whA[3][0], hB0_.v, CUR[3], 0, 0, 0); \
    a0_ = __builtin_amdgcn_mfma_f32_16x16x32_f16(whA[0][1], hB1_.v, a0_, 0, 0, 0);     \
    a1_ = __builtin_amdgcn_mfma_f32_16x16x32_f16(whA[1][1], hB1_.v, a1_, 0, 0, 0);     \
    a2_ = __builtin_amdgcn_mfma_f32_16x16x32_f16(whA[2][1], hB1_.v, a2_, 0, 0, 0);     \
    a3_ = __builtin_amdgcn_mfma_f32_16x16x32_f16(whA[3][1], hB1_.v, a3_, 0, 0, 0);     \
    a0_ = __builtin_amdgcn_mfma_f32_16x16x32_f16(whA[0][2], hB2_.v, a0_, 0, 0, 0);     \
    a1_ = __builtin_amdgcn_mfma_f32_16x16x32_f16(whA[1][2], hB2_.v, a1_, 0, 0, 0);     \
    a2_ = __builtin_amdgcn_mfma_f32_16x16x32_f16(whA[2][2], hB2_.v, a2_, 0, 0, 0);     \
    a3_ = __builtin_amdgcn_mfma_f32_16x16x32_f16(whA[3][2], hB2_.v, a3_, 0, 0, 0);     \
    a0_ = __builtin_amdgcn_mfma_f32_16x16x32_f16(whA[0][3], hB3_.v, a0_, 0, 0, 0);     \
    a1_ = __builtin_amdgcn_mfma_f32_16x16x32_f16(whA[1][3], hB3_.v, a1_, 0, 0, 0);     \
    a2_ = __builtin_amdgcn_mfma_f32_16x16x32_f16(whA[2][3], hB3_.v, a2_, 0, 0, 0);     \
    a3_ = __builtin_amdgcn_mfma_f32_16x16x32_f16(whA[3][3], hB3_.v, a3_, 0, 0, 0);     \
    if (DO_NX) { XMFMA(NXT, (SS) + 1); }                                               \
    float hhv_[4];                                                                     \
    _Pragma("unroll")                                                                  \
    for (int r_ = 0; r_ < 4; ++r_) {                                                   \
        float zi_ = a0_[r_], zf_ = a1_[r_], zg_ = a2_[r_], zo_ = a3_[r_];              \
        float ea_ = EXP2F(-zi_);                                                       \
        float eb_ = EXP2F(-zg_);                                                       \
        float sf_ = RCPF(1.0f + EXP2F(-zf_));                                          \
        float sitg_ = (1.0f - eb_) * RCPF((1.0f + ea_) * (1.0f + eb_));                \
        float c_ = fmaf(sf_, cst[r_], sitg_);                                          \
        cst[r_] = c_;                                                                  \
        float ed_ = EXP2F(-((2.0f * L2E) * c_));                                       \
        float eo_ = EXP2F(-zo_);                                                       \
        hhv_[r_] = (1.0f - ed_) * RCPF((1.0f + eo_) * (1.0f + ed_));                   \
    }                                                                                  \
    P2 q0_, q1_;                                                                       \
    q0_.p = __builtin_amdgcn_cvt_pkrtz(hhv_[0], hhv_[1]);                              \
    q1_.p = __builtin_amdgcn_cvt_pkrtz(hhv_[2], hhv_[3]);                              \
    uint2 wv_; wv_.x = q0_.u; wv_.y = q1_.u;                                           \
    *(uint2*)(lds_hr + slc * HRS + wgsw) = wv_;                                        \
    __syncthreads();                                                                   \
    slp = slc;                                                                         \
    slc = (slc + 1 == RING) ? 0 : slc + 1;                                             \
} while (0)

__global__ __launch_bounds__(512, 2) void lstm_kernel(
    const float* __restrict__ x,
    const float* __restrict__ Wih_f, const float* __restrict__ Whh_f,
    const float* __restrict__ bih_f, const float* __restrict__ bhh_f,
    const float* __restrict__ Wih_b, const float* __restrict__ Whh_b,
    const float* __restrict__ bih_b, const float* __restrict__ bhh_b,
    __fp16* __restrict__ y)
{
    const int blk = blockIdx.x;
    const int dir = blk >> 2;
    const int bg  = blk & 3;
    const int tid = threadIdx.x;
    const int w   = tid >> 6;      // wave 0..7 -> j in [16w,16w+16)
    const int l   = tid & 63;
    const int col = l & 15;        // N-dim: batch slot
    const int hi  = l >> 4;        // k-group / row-group

    const float* Wih = dir ? Wih_b : Wih_f;
    const float* Whh = dir ? Whh_b : Whh_f;
    const float* bih = dir ? bih_b : bih_f;
    const float* bhh = dir ? bhh_b : bhh_f;

    f16x8 whA[4][4];
    f16x8 wxA[4][2];
    f32x4 biasv[4];
    float cst[4] = {0.0f, 0.0f, 0.0f, 0.0f};
    #pragma unroll
    for (int m = 0; m < 4; ++m) {
        const float s = (m == 2) ? (2.0f * L2E) : L2E;
        const int rowA = (m << 7) + (w << 4) + col;
        #pragma unroll
        for (int kk = 0; kk < 4; ++kk) {
            const float* p = Whh + (size_t)rowA * 128 + kk * 32 + hi * 8;
            whA[m][kk] = cvt8s(*(const float4*)p, *(const float4*)(p + 4), s);
        }
        #pragma unroll
        for (int kk = 0; kk < 2; ++kk) {
            const float* p = Wih + (size_t)rowA * 64 + kk * 32 + hi * 8;
            wxA[m][kk] = cvt8s(*(const float4*)p, *(const float4*)(p + 4), s);
        }
        #pragma unroll
        for (int r = 0; r < 4; ++r) {
            const int rowC = (m << 7) + (w << 4) + (hi << 2) + r;
            biasv[m][r] = (bih[rowC] + bhh[rowC]) * s;
        }
    }

    __shared__ __align__(16) unsigned int lds_hr[RING * HRS];
    __shared__ __align__(16) unsigned int lds_xs[16 * XPS];

    // zero initial-h ring slot
    for (int i = tid; i < HRS; i += 512) lds_hr[(RING - 1) * HRS + i] = 0u;

    // per-thread constant addresses (same as round 8)
    const int gsw = ((hi << 4) + (col ^ hi)) << 2;             // B-frag read granule (dw)
    const int hiw = ((w & 1) << 1) + (hi >> 1);
    const int wgsw = ((w >> 1) << 8) + (((hiw << 4) + (col ^ hiw)) << 2) + ((hi & 1) << 1); // h-write (dw)

    const size_t xbase = (size_t)(bg * 16) * Cc * Tt;
    int slp = RING - 1;
    int slc = 0;

    f32x4 xaccA[4], xaccB[4];

    #pragma unroll 1
    for (int tile = 0; tile < Tt / 16; ++tile) {
        const int s0  = tile << 4;
        const int sl0 = slc;

        // ---- stage x tile (frag-major, paired channels -> dword writes) ----
        #pragma unroll
        for (int it = 0; it < 4; ++it) {
            int i = tid + (it << 9);
            int tq = i & 3, cp = (i >> 2) & 31, b = i >> 7;
            int tb = dir ? (Tt - 4 - s0 - (tq << 2)) : (s0 + (tq << 2));
            const float* rA = x + xbase + ((size_t)b * Cc + 2 * cp) * Tt + tb;
            float4 va = *(const float4*)rA;
            float4 vb = *(const float4*)(rA + Tt);
            const float* pa = (const float*)&va;
            const float* pb = (const float*)&vb;
            int kk = cp >> 4, hip = (cp >> 2) & 3, e2 = cp & 3;
            int gdst = (kk << 8) + (((hip << 4) + (b ^ hip)) << 2) + e2;
            #pragma unroll
            for (int e = 0; e < 4; ++e) {
                int ss = dir ? ((tq << 2) + 3 - e) : ((tq << 2) + e);
                P2 pk; pk.p = __builtin_amdgcn_cvt_pkrtz(pa[e], pb[e]);
                lds_xs[ss * XPS + gdst] = pk.u;
            }
        }
        __syncthreads();

        // prologue: x-projection for step 0 of this tile
        XMFMA(xaccA, 0);

        // ---- 16 recurrent steps (2x ping-pong unroll) ----
        #pragma unroll
        for (int ss = 0; ss < 16; ss += 2) {
            LSTM_STEP(ss,     xaccA, xaccB, true);
            LSTM_STEP(ss + 1, xaccB, xaccA, (ss + 1) < 15);
        }

        // ---- flush y for this tile (granule-linear LDS reads, conflict-free) ----
        #pragma unroll
        for (int it = 0; it < 8; ++it) {
            int idx = (it << 3) + w;          // 0..63 -> (ss, kkf)
            int ssf = idx >> 2, kkf = idx & 3;
            int sl = sl0 + ssf; if (sl >= RING) sl -= RING;
            uint4 v = *(const uint4*)(lds_hr + sl * HRS + (kkf << 8) + (l << 2));
            int bf = (l & 15) ^ (l >> 4);
            int j8 = (kkf << 2) + (l >> 4);
            int t = dir ? (Tt - 1 - (s0 + ssf)) : (s0 + ssf);
            *(uint4*)(y + (((size_t)(bg * 16 + bf) * Tt + t) << 8) + dir * 128 + (j8 << 3)) = v;
        }
    }
}

// ---------------- Kernel 2: attention scores (MFMA) ----------------
__global__ __launch_bounds__(512, 2) void attn_scores_kernel(
    const __fp16* __restrict__ y,
    const float* __restrict__ Wa, const float* __restrict__ ba,
    const float* __restrict__ Wu, const float* __restrict__ bu,
    float* __restrict__ scores)
{
    const int b   = blockIdx.y;
    const int t0  = blockIdx.x * 64;
    const int tid = threadIdx.x;
    const int w   = tid >> 6, l = tid & 63;
    const int col = l & 15, hi = l >> 4;

    __shared__ __fp16 y_lds[64][264];
    __shared__ float red[8][64];

    f16x8 wB[2][8];
    float bav[2], wuv[2];
    #pragma unroll
    for (int ns = 0; ns < 2; ++ns) {
        const int g = (w << 5) + (ns << 4) + col;
        #pragma unroll
        for (int kk = 0; kk < 8; ++kk) {
            const float* p = Wa + (size_t)g * 256 + kk * 32 + hi * 8;
            wB[ns][kk] = cvt8s(*(const float4*)p, *(const float4*)(p + 4), 1.0f);
        }
        bav[ns] = ba[g];
        wuv[ns] = Wu[g];
    }

    #pragma unroll
    for (int it = 0; it < 4; ++it) {
        int i = tid + it * 512;
        int tt = i >> 5, c8 = i & 31;
        uint4 v = *(const uint4*)(y + ((size_t)b * Tt + t0 + tt) * 256 + c8 * 8);
        *(uint4*)&y_lds[tt][c8 * 8] = v;
    }
    __syncthreads();

    f32x4 acc[4][2];
    #pragma unroll
    for (int ms = 0; ms < 4; ++ms)
        #pragma unroll
        for (int ns = 0; ns < 2; ++ns) {
            acc[ms][ns][0] = bav[ns]; acc[ms][ns][1] = bav[ns];
            acc[ms][ns][2] = bav[ns]; acc[ms][ns][3] = bav[ns];
        }

    #pragma unroll
    for (int ms = 0; ms < 4; ++ms) {
        #pragma unroll
        for (int kk = 0; kk < 8; ++kk) {
            P8 a;
            a.u = *(const uint4*)&y_lds[(ms << 4) + col][kk * 32 + hi * 8];
            acc[ms][0] = __builtin_amdgcn_mfma_f32_16x16x32_f16(a.v, wB[0][kk], acc[ms][0], 0, 0, 0);
            acc[ms][1] = __builtin_amdgcn_mfma_f32_16x16x32_f16(a.v, wB[1][kk], acc[ms][1], 0, 0, 0);
        }
    }

    #pragma unroll
    for (int ms = 0; ms < 4; ++ms) {
        float pr[4];
        #pragma unroll
        for (int r = 0; r < 4; ++r) {
            pr[r] = wuv[0] * ftanh(acc[ms][0][r]) + wuv[1] * ftanh(acc[ms][1][r]);
            pr[r] += __shfl_xor(pr[r], 1, 64);
            pr[r] += __shfl_xor(pr[r], 2, 64);
            pr[r] += __shfl_xor(pr[r], 4, 64);
            pr[r] += __shfl_xor(pr[r], 8, 64);
        }
        if (col == 0) {
            #pragma unroll
            for (int r = 0; r < 4; ++r)
                red[w][(ms << 4) + (hi << 2) + r] = pr[r];
        }
    }
    __syncthreads();
    if (tid < 64) {
        float ssum = bu[0];
        #pragma unroll
        for (int wv = 0; wv < 8; ++wv) ssum += red[wv][tid];
        scores[(size_t)b * Tt + t0 + tid] = ssum;
    }
}

// ---------------- Kernel 3: softmax + weighted sum ----------------
__global__ __launch_bounds__(256) void attn_out_kernel(
    const __fp16* __restrict__ y,
    const float* __restrict__ scores,
    float* __restrict__ out)
{
    const int b = blockIdx.x;
    const int tid = threadIdx.x;
    const int lane = tid & 63, wid = tid >> 6;
    __shared__ float wls[2048];
    __shared__ float red[4];

    float m = -1e30f;
    for (int t = tid; t < Tt; t += 256) m = fmaxf(m, scores[(size_t)b * Tt + t]);
    #pragma unroll
    for (int off = 32; off >= 1; off >>= 1) m = fmaxf(m, __shfl_xor(m, off, 64));
    if (lane == 0) red[wid] = m;
    __syncthreads();
    m = fmaxf(fmaxf(red[0], red[1]), fmaxf(red[2], red[3]));
    __syncthreads();

    float sum = 0.0f;
    for (int t = tid; t < Tt; t += 256) {
        float e = __expf(scores[(size_t)b * Tt + t] - m);
        wls[t] = e;
        sum += e;
    }
    #pragma unroll
    for (int off = 32; off >= 1; off >>= 1) sum += __shfl_xor(sum, off, 64);
    if (lane == 0) red[wid] = sum;
    __syncthreads();
    const float inv = 1.0f / (red[0] + red[1] + red[2] + red[3]);

    const __fp16* yb = y + (size_t)b * Tt * 256 + tid;
    float acc = 0.0f;
    for (int t = 0; t < Tt; ++t) {
        acc += wls[t] * (float)yb[(size_t)t * 256];
    }
    out[b * 256 + tid] = acc * inv;
}

extern "C" void kernel_launch(void* const* d_in, const int* in_sizes, int n_in,
                              void* d_out, int out_size, void* d_ws, size_t ws_size,
                              hipStream_t stream) {
    const float* x     = (const float*)d_in[0];
    const float* Wih_f = (const float*)d_in[1];
    const float* Whh_f = (const float*)d_in[2];
    const float* bih_f = (const float*)d_in[3];
    const float* bhh_f = (const float*)d_in[4];
    const float* Wih_b = (const float*)d_in[5];
    const float* Whh_b = (const float*)d_in[6];
    const float* bih_b = (const float*)d_in[7];
    const float* bhh_b = (const float*)d_in[8];
    const float* Wa    = (const float*)d_in[9];
    const float* ba    = (const float*)d_in[10];
    const float* Wu    = (const float*)d_in[11];
    const float* bu    = (const float*)d_in[12];
    float* out = (float*)d_out;

    // workspace: y (B*T*256 f16 = 64 MiB) | scores (B*T f32 = 0.5 MiB)
    __fp16* y = (__fp16*)d_ws;
    float* scores = (float*)((char*)d_ws + (size_t)Bb * Tt * 256 * sizeof(__fp16));

    hipLaunchKernelGGL(lstm_kernel, dim3(8), dim3(512), 0, stream,
                       x, Wih_f, Whh_f, bih_f, bhh_f, Wih_b, Whh_b, bih_b, bhh_b, y);
    hipLaunchKernelGGL(attn_scores_kernel, dim3(Tt / 64, Bb), dim3(512), 0, stream,
                       y, Wa, ba, Wu, bu, scores);
    hipLaunchKernelGGL(attn_out_kernel, dim3(Bb), dim3(256), 0, stream, y, scores, out);
}